// Round 5
// baseline (340.538 us; speedup 1.0000x reference)
//
#include <hip/hip_runtime.h>

static constexpr float DEG2RAD = 0.017453292519943295f;

__global__ void __launch_bounds__(256) node_ef_kernel(
    const float* __restrict__ x, const float* __restrict__ xymean,
    const float* __restrict__ xystd, float2* __restrict__ ef, int n)
{
    int i = blockIdx.x * 256 + threadIdx.x;
    if (i >= n) return;
    float vm = fmaf(x[i * 6 + 0], xystd[0], xymean[0]);
    float va = fmaf(x[i * 6 + 1], xystd[1], xymean[1]) * DEG2RAD;
    float s, c;
    sincosf(va, &s, &c);
    ef[i] = make_float2(vm * c, vm * s);
}

__global__ void __launch_bounds__(256) edge_kernel(
    const int* __restrict__ eidx, const float2* __restrict__ eattr,
    const float2* __restrict__ ef, const float* __restrict__ edgemean,
    const float* __restrict__ edgestd, float* __restrict__ agg, int ne)
{
    int e = blockIdx.x * 256 + threadIdx.x;
    if (e >= ne) return;
    int s = eidx[e];        // src
    int d = eidx[ne + e];   // dst
    float2 ea = eattr[e];
    float r  = fmaf(ea.x, edgestd[0], edgemean[0]);
    float xr = fmaf(ea.y, edgestd[1], edgemean[1]);
    float inv = 1.0f / fmaf(r, r, xr * xr);
    float g = r * inv;
    float b = -xr * inv;
    float2 efi = ef[s];
    float2 efj = ef[d];
    float ei_ = efi.x, fi = efi.y, ej_ = efj.x, fj = efj.y;
    // A = e_i*e_j - e_i^2 + f_i*f_j - f_i^2 ; B = f_i*e_j - e_i*f_j
    float A1 = fmaf(ei_, ej_ - ei_, fi * (fj - fi));
    float B1 = fmaf(fi, ej_, -ei_ * fj);
    // direction i=src, j=dst
    atomicAdd(&agg[2 * s],     fmaf(g, A1, b * B1));   // P
    atomicAdd(&agg[2 * s + 1], fmaf(g, B1, -b * A1));  // Q
    // direction i=dst, j=src (B2 = -B1)
    float A2 = fmaf(ej_, ei_ - ej_, fj * (fi - fj));
    atomicAdd(&agg[2 * d],     fmaf(g, A2, -b * B1));
    atomicAdd(&agg[2 * d + 1], fmaf(-g, B1, -b * A2));
}

__global__ void __launch_bounds__(256) reduce_kernel(
    const float* __restrict__ x, const float* __restrict__ y,
    const float* __restrict__ xymean, const float* __restrict__ xystd,
    const float* __restrict__ agg, float* __restrict__ out, int n)
{
    int i = blockIdx.x * 256 + threadIdx.x;
    float v = 0.0f;
    if (i < n) {
        float xd2 = fmaf(x[i * 6 + 2], xystd[2], xymean[2]);
        float xd3 = fmaf(x[i * 6 + 3], xystd[3], xymean[3]);
        float dP = xd2 - agg[2 * i];
        float dQ = xd3 - agg[2 * i + 1];
        float dpq = fmaf(dP, dP, dQ * dQ);
        float msep = 0.0f;
        #pragma unroll
        for (int c = 0; c < 6; ++c) {
            float dxy = x[i * 6 + c] - y[i * 6 + c];
            msep = fmaf(dxy, dxy, msep);
        }
        // out = 0.5*mse_sum/(6N) + 0.01*dpq_sum/N  (linear -> fold per thread)
        v = dpq * (0.01f / (float)n) + msep * (0.5f / (6.0f * (float)n));
    }
    #pragma unroll
    for (int off = 32; off; off >>= 1) v += __shfl_down(v, off, 64);
    __shared__ float ls[4];
    int lane = threadIdx.x & 63, wv = threadIdx.x >> 6;
    if (lane == 0) ls[wv] = v;
    __syncthreads();
    if (threadIdx.x == 0) atomicAdd(out, ls[0] + ls[1] + ls[2] + ls[3]);
}

extern "C" void kernel_launch(void* const* d_in, const int* in_sizes, int n_in,
                              void* d_out, int out_size, void* d_ws, size_t ws_size,
                              hipStream_t stream) {
    const float* x        = (const float*)d_in[0];
    const int*   eidx     = (const int*)d_in[1];
    const float* eattr    = (const float*)d_in[2];
    const float* y        = (const float*)d_in[3];
    const float* xymean   = (const float*)d_in[4];
    const float* xystd    = (const float*)d_in[5];
    const float* edgemean = (const float*)d_in[6];
    const float* edgestd  = (const float*)d_in[7];
    float* out = (float*)d_out;

    const int n = in_sizes[0] / 6;   // 100000 nodes
    const int e = in_sizes[2] / 2;   // 1600000 edges (from edge_attr)

    float*  agg = (float*)d_ws;                                      // 2n floats
    float2* ef  = (float2*)((char*)d_ws + (size_t)2 * n * sizeof(float)); // n float2

    hipMemsetAsync(agg, 0, (size_t)2 * n * sizeof(float), stream);
    hipMemsetAsync(out, 0, sizeof(float), stream);

    node_ef_kernel<<<(n + 255) / 256, 256, 0, stream>>>(x, xymean, xystd, ef, n);
    edge_kernel<<<(e + 255) / 256, 256, 0, stream>>>(
        eidx, (const float2*)eattr, ef, edgemean, edgestd, agg, e);
    reduce_kernel<<<(n + 255) / 256, 256, 0, stream>>>(
        x, y, xymean, xystd, agg, out, n);
}

// Round 6
// 336.960 us; speedup vs baseline: 1.0106x; 1.0106x over previous
//
#include <hip/hip_runtime.h>

static constexpr float DEG2RAD = 0.017453292519943295f;
static constexpr int NXCD = 8;

__device__ __forceinline__ unsigned get_xcc() {
    unsigned x;
    asm("s_getreg_b32 %0, hwreg(HW_REG_XCC_ID)" : "=s"(x));
    return x & (NXCD - 1);
}

__global__ void __launch_bounds__(256) node_ef_kernel(
    const float* __restrict__ x, const float* __restrict__ xymean,
    const float* __restrict__ xystd, float2* __restrict__ ef, int n)
{
    int i = blockIdx.x * 256 + threadIdx.x;
    if (i >= n) return;
    float vm = fmaf(x[i * 6 + 0], xystd[0], xymean[0]);
    float va = fmaf(x[i * 6 + 1], xystd[1], xymean[1]) * DEG2RAD;
    float s, c;
    sincosf(va, &s, &c);
    ef[i] = make_float2(vm * c, vm * s);
}

// REP=true: per-XCD replicated agg + workgroup-scope atomics (performed at the
// XCD's own TCC — every block touching copy k is physically on XCD k, so that
// L2 is the single serialization point; no memory-side forwarding).
// REP=false: single copy + agent-scope atomics (fallback if ws too small).
template <bool REP>
__global__ void __launch_bounds__(256) edge_kernel(
    const int* __restrict__ eidx, const float2* __restrict__ eattr,
    const float2* __restrict__ ef, const float* __restrict__ edgemean,
    const float* __restrict__ edgestd, float* __restrict__ agg, int ne, int n)
{
    int e = blockIdx.x * 256 + threadIdx.x;
    if (e >= ne) return;
    float* aggx = agg;
    if (REP) aggx = agg + (size_t)get_xcc() * 2u * (unsigned)n;
    int s = eidx[e];        // src
    int d = eidx[ne + e];   // dst
    float2 ea = eattr[e];
    float r  = fmaf(ea.x, edgestd[0], edgemean[0]);
    float xr = fmaf(ea.y, edgestd[1], edgemean[1]);
    float inv = 1.0f / fmaf(r, r, xr * xr);
    float g = r * inv;
    float b = -xr * inv;
    float2 efi = ef[s];
    float2 efj = ef[d];
    float ei_ = efi.x, fi = efi.y, ej_ = efj.x, fj = efj.y;
    // A = e_i*e_j - e_i^2 + f_i*f_j - f_i^2 ; B = f_i*e_j - e_i*f_j
    float A1 = fmaf(ei_, ej_ - ei_, fi * (fj - fi));
    float B1 = fmaf(fi, ej_, -ei_ * fj);
    float A2 = fmaf(ej_, ei_ - ej_, fj * (fi - fj));
    float Ps = fmaf(g, A1, b * B1);    // P into src
    float Qs = fmaf(g, B1, -b * A1);   // Q into src
    float Pd = fmaf(g, A2, -b * B1);   // P into dst (B2 = -B1)
    float Qd = fmaf(-g, B1, -b * A2);  // Q into dst
    if (REP) {
        __hip_atomic_fetch_add(&aggx[2 * s],     Ps, __ATOMIC_RELAXED, __HIP_MEMORY_SCOPE_WORKGROUP);
        __hip_atomic_fetch_add(&aggx[2 * s + 1], Qs, __ATOMIC_RELAXED, __HIP_MEMORY_SCOPE_WORKGROUP);
        __hip_atomic_fetch_add(&aggx[2 * d],     Pd, __ATOMIC_RELAXED, __HIP_MEMORY_SCOPE_WORKGROUP);
        __hip_atomic_fetch_add(&aggx[2 * d + 1], Qd, __ATOMIC_RELAXED, __HIP_MEMORY_SCOPE_WORKGROUP);
    } else {
        atomicAdd(&aggx[2 * s],     Ps);
        atomicAdd(&aggx[2 * s + 1], Qs);
        atomicAdd(&aggx[2 * d],     Pd);
        atomicAdd(&aggx[2 * d + 1], Qd);
    }
}

template <int R>
__global__ void __launch_bounds__(256) reduce_kernel(
    const float* __restrict__ x, const float* __restrict__ y,
    const float* __restrict__ xymean, const float* __restrict__ xystd,
    const float2* __restrict__ agg, float* __restrict__ out, int n)
{
    int i = blockIdx.x * 256 + threadIdx.x;
    float v = 0.0f;
    if (i < n) {
        float P = 0.0f, Q = 0.0f;
        #pragma unroll
        for (int r = 0; r < R; ++r) {
            float2 a = agg[(size_t)r * n + i];
            P += a.x;
            Q += a.y;
        }
        float xd2 = fmaf(x[i * 6 + 2], xystd[2], xymean[2]);
        float xd3 = fmaf(x[i * 6 + 3], xystd[3], xymean[3]);
        float dP = xd2 - P;
        float dQ = xd3 - Q;
        float dpq = fmaf(dP, dP, dQ * dQ);
        float msep = 0.0f;
        #pragma unroll
        for (int c = 0; c < 6; ++c) {
            float dxy = x[i * 6 + c] - y[i * 6 + c];
            msep = fmaf(dxy, dxy, msep);
        }
        // out = 0.5*mse_sum/(6N) + 0.01*dpq_sum/N  (linear -> fold per thread)
        v = dpq * (0.01f / (float)n) + msep * (0.5f / (6.0f * (float)n));
    }
    #pragma unroll
    for (int off = 32; off; off >>= 1) v += __shfl_down(v, off, 64);
    __shared__ float ls[4];
    int lane = threadIdx.x & 63, wv = threadIdx.x >> 6;
    if (lane == 0) ls[wv] = v;
    __syncthreads();
    if (threadIdx.x == 0) atomicAdd(out, ls[0] + ls[1] + ls[2] + ls[3]);
}

extern "C" void kernel_launch(void* const* d_in, const int* in_sizes, int n_in,
                              void* d_out, int out_size, void* d_ws, size_t ws_size,
                              hipStream_t stream) {
    const float* x        = (const float*)d_in[0];
    const int*   eidx     = (const int*)d_in[1];
    const float* eattr    = (const float*)d_in[2];
    const float* y        = (const float*)d_in[3];
    const float* xymean   = (const float*)d_in[4];
    const float* xystd    = (const float*)d_in[5];
    const float* edgemean = (const float*)d_in[6];
    const float* edgestd  = (const float*)d_in[7];
    float* out = (float*)d_out;

    const int n = in_sizes[0] / 6;   // 100000 nodes
    const int e = in_sizes[2] / 2;   // 1600000 edges (from edge_attr)

    const size_t agg_rep_bytes = (size_t)NXCD * 2 * n * sizeof(float); // 6.4 MB
    const size_t ef_bytes      = (size_t)n * sizeof(float2);           // 0.8 MB
    const bool rep = ws_size >= agg_rep_bytes + ef_bytes;

    float*  agg = (float*)d_ws;
    size_t  agg_bytes = rep ? agg_rep_bytes : (size_t)2 * n * sizeof(float);
    float2* ef  = (float2*)((char*)d_ws + agg_bytes);

    hipMemsetAsync(agg, 0, agg_bytes, stream);
    hipMemsetAsync(out, 0, sizeof(float), stream);

    node_ef_kernel<<<(n + 255) / 256, 256, 0, stream>>>(x, xymean, xystd, ef, n);
    if (rep) {
        edge_kernel<true><<<(e + 255) / 256, 256, 0, stream>>>(
            eidx, (const float2*)eattr, ef, edgemean, edgestd, agg, e, n);
        reduce_kernel<NXCD><<<(n + 255) / 256, 256, 0, stream>>>(
            x, y, xymean, xystd, (const float2*)agg, out, n);
    } else {
        edge_kernel<false><<<(e + 255) / 256, 256, 0, stream>>>(
            eidx, (const float2*)eattr, ef, edgemean, edgestd, agg, e, n);
        reduce_kernel<1><<<(n + 255) / 256, 256, 0, stream>>>(
            x, y, xymean, xystd, (const float2*)agg, out, n);
    }
}

// Round 8
// 117.346 us; speedup vs baseline: 2.9020x; 2.8715x over previous
//
#include <hip/hip_runtime.h>

static constexpr float DEG2RAD = 0.017453292519943295f;
static constexpr int B_N    = 8192;  // nodes per bucket -> 64KB LDS of float2
static constexpr int MAX_NS = 20;    // max edge-list splits

__global__ void __launch_bounds__(256) node_ef_kernel(
    const float* __restrict__ x, const float* __restrict__ xymean,
    const float* __restrict__ xystd, float2* __restrict__ ef, int n)
{
    int i = blockIdx.x * 256 + threadIdx.x;
    if (i >= n) return;
    float vm = fmaf(x[i * 6 + 0], xystd[0], xymean[0]);
    float va = fmaf(x[i * 6 + 1], xystd[1], xymean[1]) * DEG2RAD;
    float s, c;
    sincosf(va, &s, &c);
    ef[i] = make_float2(vm * c, vm * s);
}

// Bucketed scan: block (split s, bucket b) scans edge slice s, accumulates
// messages for nodes in [b*B_N, b*B_N+B_N) into LDS (ds_add_f32), then
// streams the 64KB histogram to partial[blockIdx]. No global atomics.
__global__ void __launch_bounds__(1024) scan_kernel(
    const int* __restrict__ src, const int* __restrict__ dst,
    const float2* __restrict__ eattr, const float2* __restrict__ ef,
    const float* __restrict__ edgemean, const float* __restrict__ edgestd,
    float2* __restrict__ partial, int ne, int nb, int slice)
{
    __shared__ float2 sAgg[B_N];
    const int b    = blockIdx.x % nb;   // bucket (split-major: same slice adjacent -> L3 locality)
    const int sp   = blockIdx.x / nb;   // split
    const int base = b * B_N;
    for (int l = threadIdx.x; l < B_N; l += 1024) sAgg[l] = make_float2(0.f, 0.f);
    __syncthreads();
    const int e0 = sp * slice;
    const int e1 = min(ne, e0 + slice);
    const float em0 = edgemean[0], em1 = edgemean[1];
    const float es0 = edgestd[0],  es1 = edgestd[1];
    for (int e = e0 + (int)threadIdx.x; e < e1; e += 1024) {
        int si = src[e];
        int di = dst[e];
        unsigned ls = (unsigned)(si - base);
        unsigned ld = (unsigned)(di - base);
        bool hs = ls < (unsigned)B_N;
        bool hd = ld < (unsigned)B_N;
        if (!(hs || hd)) continue;
        float2 ea = eattr[e];
        float r  = fmaf(ea.x, es0, em0);
        float xr = fmaf(ea.y, es1, em1);
        float inv = 1.0f / fmaf(r, r, xr * xr);
        float g  = r * inv;
        float bb = -xr * inv;
        float2 efi = ef[si];
        float2 efj = ef[di];
        float ei_ = efi.x, fi = efi.y, ej_ = efj.x, fj = efj.y;
        // A = e_i*e_j - e_i^2 + f_i*f_j - f_i^2 ; B = f_i*e_j - e_i*f_j
        float A1 = fmaf(ei_, ej_ - ei_, fi * (fj - fi));
        float B1 = fmaf(fi, ej_, -ei_ * fj);
        if (hs) {
            atomicAdd(&sAgg[ls].x, fmaf(g, A1, bb * B1));   // P into src
            atomicAdd(&sAgg[ls].y, fmaf(g, B1, -bb * A1));  // Q into src
        }
        if (hd) {
            float A2 = fmaf(ej_, ei_ - ej_, fj * (fi - fj));
            atomicAdd(&sAgg[ld].x, fmaf(g, A2, -bb * B1));  // P into dst (B2=-B1)
            atomicAdd(&sAgg[ld].y, fmaf(-g, B1, -bb * A2)); // Q into dst
        }
    }
    __syncthreads();
    float2* out = partial + (size_t)blockIdx.x * B_N;
    for (int l = threadIdx.x; l < B_N; l += 1024) out[l] = sAgg[l];
}

// Fallback (small ws): plain device atomics, as benched in R5 (~320us).
__global__ void __launch_bounds__(256) edge_atomic_kernel(
    const int* __restrict__ eidx, const float2* __restrict__ eattr,
    const float2* __restrict__ ef, const float* __restrict__ edgemean,
    const float* __restrict__ edgestd, float* __restrict__ agg, int ne)
{
    int e = blockIdx.x * 256 + threadIdx.x;
    if (e >= ne) return;
    int s = eidx[e];
    int d = eidx[ne + e];
    float2 ea = eattr[e];
    float r  = fmaf(ea.x, edgestd[0], edgemean[0]);
    float xr = fmaf(ea.y, edgestd[1], edgemean[1]);
    float inv = 1.0f / fmaf(r, r, xr * xr);
    float g = r * inv;
    float b = -xr * inv;
    float2 efi = ef[s];
    float2 efj = ef[d];
    float ei_ = efi.x, fi = efi.y, ej_ = efj.x, fj = efj.y;
    float A1 = fmaf(ei_, ej_ - ei_, fi * (fj - fi));
    float B1 = fmaf(fi, ej_, -ei_ * fj);
    float A2 = fmaf(ej_, ei_ - ej_, fj * (fi - fj));
    atomicAdd(&agg[2 * s],     fmaf(g, A1, b * B1));
    atomicAdd(&agg[2 * s + 1], fmaf(g, B1, -b * A1));
    atomicAdd(&agg[2 * d],     fmaf(g, A2, -b * B1));
    atomicAdd(&agg[2 * d + 1], fmaf(-g, B1, -b * A2));
}

// Final: fold NS partials per node + fused MSE, single scalar out.
// ns==0 means agg is a single dense float2[n] (atomic fallback path).
__global__ void __launch_bounds__(256) reduce_kernel(
    const float* __restrict__ x, const float* __restrict__ y,
    const float* __restrict__ xymean, const float* __restrict__ xystd,
    const float2* __restrict__ partial, float* __restrict__ out,
    int n, int nb, int ns)
{
    int i = blockIdx.x * 256 + threadIdx.x;
    float v = 0.0f;
    if (i < n) {
        float P = 0.0f, Q = 0.0f;
        if (ns > 0) {
            int b = i / B_N;
            int l = i & (B_N - 1);
            for (int s = 0; s < ns; ++s) {
                float2 a = partial[((size_t)s * nb + b) * B_N + l];
                P += a.x;
                Q += a.y;
            }
        } else {
            float2 a = partial[i];
            P = a.x;
            Q = a.y;
        }
        float xd2 = fmaf(x[i * 6 + 2], xystd[2], xymean[2]);
        float xd3 = fmaf(x[i * 6 + 3], xystd[3], xymean[3]);
        float dP = xd2 - P;
        float dQ = xd3 - Q;
        float dpq = fmaf(dP, dP, dQ * dQ);
        float msep = 0.0f;
        #pragma unroll
        for (int c = 0; c < 6; ++c) {
            float dxy = x[i * 6 + c] - y[i * 6 + c];
            msep = fmaf(dxy, dxy, msep);
        }
        // out = 0.5*mse_sum/(6N) + 0.01*dpq_sum/N
        v = dpq * (0.01f / (float)n) + msep * (0.5f / (6.0f * (float)n));
    }
    #pragma unroll
    for (int off = 32; off; off >>= 1) v += __shfl_down(v, off, 64);
    __shared__ float ls_[4];
    int lane = threadIdx.x & 63, wv = threadIdx.x >> 6;
    if (lane == 0) ls_[wv] = v;
    __syncthreads();
    if (threadIdx.x == 0) atomicAdd(out, ls_[0] + ls_[1] + ls_[2] + ls_[3]);
}

extern "C" void kernel_launch(void* const* d_in, const int* in_sizes, int n_in,
                              void* d_out, int out_size, void* d_ws, size_t ws_size,
                              hipStream_t stream) {
    const float* x        = (const float*)d_in[0];
    const int*   eidx     = (const int*)d_in[1];
    const float* eattr    = (const float*)d_in[2];
    const float* y        = (const float*)d_in[3];
    const float* xymean   = (const float*)d_in[4];
    const float* xystd    = (const float*)d_in[5];
    const float* edgemean = (const float*)d_in[6];
    const float* edgestd  = (const float*)d_in[7];
    float* out = (float*)d_out;

    const int n  = in_sizes[0] / 6;   // 100000 nodes
    const int ne = in_sizes[2] / 2;   // 1600000 edges

    const int nb = (n + B_N - 1) / B_N;                    // 13 buckets
    const size_t ef_bytes  = (size_t)n * sizeof(float2);   // 0.8 MB
    const size_t per_split = (size_t)nb * B_N * sizeof(float2); // 0.85 MB

    int ns = 0;
    if (ws_size > ef_bytes) {
        size_t fit = (ws_size - ef_bytes) / per_split;
        ns = (fit > (size_t)MAX_NS) ? MAX_NS : (int)fit;
    }

    (void)hipMemsetAsync(out, 0, sizeof(float), stream);

    if (ns >= 1) {
        float2* partial = (float2*)d_ws;
        float2* ef = (float2*)((char*)d_ws + per_split * ns);
        node_ef_kernel<<<(n + 255) / 256, 256, 0, stream>>>(x, xymean, xystd, ef, n);
        const int slice = (ne + ns - 1) / ns;
        scan_kernel<<<nb * ns, 1024, 0, stream>>>(
            eidx, eidx + ne, (const float2*)eattr, ef, edgemean, edgestd,
            partial, ne, nb, slice);
        reduce_kernel<<<(n + 255) / 256, 256, 0, stream>>>(
            x, y, xymean, xystd, partial, out, n, nb, ns);
    } else {
        float2* agg = (float2*)d_ws;
        float2* ef = (float2*)((char*)d_ws + (size_t)n * sizeof(float2));
        (void)hipMemsetAsync(agg, 0, (size_t)n * sizeof(float2), stream);
        node_ef_kernel<<<(n + 255) / 256, 256, 0, stream>>>(x, xymean, xystd, ef, n);
        edge_atomic_kernel<<<(ne + 255) / 256, 256, 0, stream>>>(
            eidx, (const float2*)eattr, ef, edgemean, edgestd, (float*)agg, ne);
        reduce_kernel<<<(n + 255) / 256, 256, 0, stream>>>(
            x, y, xymean, xystd, agg, out, n, nb, 0);
    }
}

// Round 9
// 92.389 us; speedup vs baseline: 3.6859x; 1.2701x over previous
//
#include <hip/hip_runtime.h>

static constexpr float DEG2RAD = 0.017453292519943295f;
static constexpr int B_N    = 8192;  // nodes per bucket -> 64KB LDS of float2
static constexpr int MAX_NS = 40;    // max edge-list splits (2 blocks/CU)

__global__ void __launch_bounds__(256) node_ef_kernel(
    const float* __restrict__ x, const float* __restrict__ xymean,
    const float* __restrict__ xystd, float2* __restrict__ ef, int n)
{
    int i = blockIdx.x * 256 + threadIdx.x;
    if (i >= n) return;
    float vm = fmaf(x[i * 6 + 0], xystd[0], xymean[0]);
    float va = fmaf(x[i * 6 + 1], xystd[1], xymean[1]) * DEG2RAD;
    float s, c;
    sincosf(va, &s, &c);
    ef[i] = make_float2(vm * c, vm * s);
}

// Bucketed scan. SW=true: slice id pinned to XCD (sp%8 == hw blockIdx%8) so
// all nb blocks scanning the same edge slice share ONE L2 -> each slice is
// fetched beyond-L2 exactly once instead of once per XCD.
template <bool SW>
__global__ void __launch_bounds__(1024) scan_kernel(
    const int* __restrict__ src, const int* __restrict__ dst,
    const float2* __restrict__ eattr, const float2* __restrict__ ef,
    const float* __restrict__ edgemean, const float* __restrict__ edgestd,
    float2* __restrict__ partial, int ne, int nb, int slice)
{
    __shared__ float2 sAgg[B_N];
    int b, sp;
    if (SW) {
        int xp = blockIdx.x & 7, q = blockIdx.x >> 3;
        b  = q % nb;
        sp = (q / nb) * 8 + xp;
    } else {
        b  = blockIdx.x % nb;
        sp = blockIdx.x / nb;
    }
    const int base = b * B_N;
    for (int l = threadIdx.x; l < B_N; l += 1024) sAgg[l] = make_float2(0.f, 0.f);
    __syncthreads();
    const int e0 = sp * slice;
    const int e1 = min(ne, e0 + slice);
    const float em0 = edgemean[0], em1 = edgemean[1];
    const float es0 = edgestd[0],  es1 = edgestd[1];

    auto process = [&](int si, int di, int e) {
        unsigned ls = (unsigned)(si - base);
        unsigned ld = (unsigned)(di - base);
        bool hs = ls < (unsigned)B_N;
        bool hd = ld < (unsigned)B_N;
        if (!(hs || hd)) return;
        float2 ea = eattr[e];
        float r  = fmaf(ea.x, es0, em0);
        float xr = fmaf(ea.y, es1, em1);
        float inv = 1.0f / fmaf(r, r, xr * xr);
        float g  = r * inv;
        float bb = -xr * inv;
        float2 efi = ef[si];
        float2 efj = ef[di];
        float ei_ = efi.x, fi = efi.y, ej_ = efj.x, fj = efj.y;
        // A = e_i*e_j - e_i^2 + f_i*f_j - f_i^2 ; B = f_i*e_j - e_i*f_j
        float A1 = fmaf(ei_, ej_ - ei_, fi * (fj - fi));
        float B1 = fmaf(fi, ej_, -ei_ * fj);
        if (hs) {
            atomicAdd(&sAgg[ls].x, fmaf(g, A1, bb * B1));   // P into src
            atomicAdd(&sAgg[ls].y, fmaf(g, B1, -bb * A1));  // Q into src
        }
        if (hd) {
            float A2 = fmaf(ej_, ei_ - ej_, fj * (fi - fj));
            atomicAdd(&sAgg[ld].x, fmaf(g, A2, -bb * B1));  // P into dst (B2=-B1)
            atomicAdd(&sAgg[ld].y, fmaf(-g, B1, -bb * A2)); // Q into dst
        }
    };

    // slice and ne are even -> pairs never straddle e1.
    for (int e = e0 + 2 * (int)threadIdx.x; e < e1; e += 2048) {
        int2 ss = *(const int2*)(src + e);
        int2 dd = *(const int2*)(dst + e);
        process(ss.x, dd.x, e);
        process(ss.y, dd.y, e + 1);
    }
    __syncthreads();
    float2* outp = partial + ((size_t)sp * nb + b) * B_N;
    for (int l = threadIdx.x; l < B_N; l += 1024) outp[l] = sAgg[l];
}

// Fallback (tiny ws): plain device atomics (~320us, R5).
__global__ void __launch_bounds__(256) edge_atomic_kernel(
    const int* __restrict__ eidx, const float2* __restrict__ eattr,
    const float2* __restrict__ ef, const float* __restrict__ edgemean,
    const float* __restrict__ edgestd, float* __restrict__ agg, int ne)
{
    int e = blockIdx.x * 256 + threadIdx.x;
    if (e >= ne) return;
    int s = eidx[e];
    int d = eidx[ne + e];
    float2 ea = eattr[e];
    float r  = fmaf(ea.x, edgestd[0], edgemean[0]);
    float xr = fmaf(ea.y, edgestd[1], edgemean[1]);
    float inv = 1.0f / fmaf(r, r, xr * xr);
    float g = r * inv;
    float b = -xr * inv;
    float2 efi = ef[s];
    float2 efj = ef[d];
    float ei_ = efi.x, fi = efi.y, ej_ = efj.x, fj = efj.y;
    float A1 = fmaf(ei_, ej_ - ei_, fi * (fj - fi));
    float B1 = fmaf(fi, ej_, -ei_ * fj);
    float A2 = fmaf(ej_, ei_ - ej_, fj * (fi - fj));
    atomicAdd(&agg[2 * s],     fmaf(g, A1, b * B1));
    atomicAdd(&agg[2 * s + 1], fmaf(g, B1, -b * A1));
    atomicAdd(&agg[2 * d],     fmaf(g, A2, -b * B1));
    atomicAdd(&agg[2 * d + 1], fmaf(-g, B1, -b * A2));
}

// Fold ns partials per node + fused MSE -> single scalar.
// ns==0: partial is a dense float2[n] (atomic fallback).
__global__ void __launch_bounds__(256) reduce_kernel(
    const float* __restrict__ x, const float* __restrict__ y,
    const float* __restrict__ xymean, const float* __restrict__ xystd,
    const float2* __restrict__ partial, float* __restrict__ out,
    int n, int nb, int ns)
{
    int i = blockIdx.x * 256 + threadIdx.x;
    float v = 0.0f;
    if (i < n) {
        float P = 0.0f, Q = 0.0f;
        if (ns > 0) {
            int b = i / B_N;
            int l = i & (B_N - 1);
            const float2* p = partial + (size_t)b * B_N + l;
            for (int s = 0; s < ns; ++s) {
                float2 a = p[(size_t)s * nb * B_N];
                P += a.x;
                Q += a.y;
            }
        } else {
            float2 a = partial[i];
            P = a.x;
            Q = a.y;
        }
        float xd2 = fmaf(x[i * 6 + 2], xystd[2], xymean[2]);
        float xd3 = fmaf(x[i * 6 + 3], xystd[3], xymean[3]);
        float dP = xd2 - P;
        float dQ = xd3 - Q;
        float dpq = fmaf(dP, dP, dQ * dQ);
        float msep = 0.0f;
        #pragma unroll
        for (int c = 0; c < 6; ++c) {
            float dxy = x[i * 6 + c] - y[i * 6 + c];
            msep = fmaf(dxy, dxy, msep);
        }
        // out = 0.5*mse_sum/(6N) + 0.01*dpq_sum/N
        v = dpq * (0.01f / (float)n) + msep * (0.5f / (6.0f * (float)n));
    }
    #pragma unroll
    for (int off = 32; off; off >>= 1) v += __shfl_down(v, off, 64);
    __shared__ float ls_[4];
    int lane = threadIdx.x & 63, wv = threadIdx.x >> 6;
    if (lane == 0) ls_[wv] = v;
    __syncthreads();
    if (threadIdx.x == 0) atomicAdd(out, ls_[0] + ls_[1] + ls_[2] + ls_[3]);
}

extern "C" void kernel_launch(void* const* d_in, const int* in_sizes, int n_in,
                              void* d_out, int out_size, void* d_ws, size_t ws_size,
                              hipStream_t stream) {
    const float* x        = (const float*)d_in[0];
    const int*   eidx     = (const int*)d_in[1];
    const float* eattr    = (const float*)d_in[2];
    const float* y        = (const float*)d_in[3];
    const float* xymean   = (const float*)d_in[4];
    const float* xystd    = (const float*)d_in[5];
    const float* edgemean = (const float*)d_in[6];
    const float* edgestd  = (const float*)d_in[7];
    float* out = (float*)d_out;

    const int n  = in_sizes[0] / 6;   // 100000 nodes
    const int ne = in_sizes[2] / 2;   // 1600000 edges

    const int nb = (n + B_N - 1) / B_N;                         // 13 buckets
    const size_t ef_bytes  = (size_t)n * sizeof(float2);        // 0.8 MB
    const size_t per_split = (size_t)nb * B_N * sizeof(float2); // 0.85 MB

    int ns = 0;
    if (ws_size > ef_bytes) {
        size_t fit = (ws_size - ef_bytes) / per_split;
        ns = (fit > (size_t)MAX_NS) ? MAX_NS : (int)fit;
    }
    bool sw = false;
    if (ns >= 8) { ns &= ~7; sw = true; }   // multiple of 8 -> bijective swizzle

    (void)hipMemsetAsync(out, 0, sizeof(float), stream);

    if (ns >= 1) {
        float2* partial = (float2*)d_ws;
        float2* ef = (float2*)((char*)d_ws + per_split * ns);
        node_ef_kernel<<<(n + 255) / 256, 256, 0, stream>>>(x, xymean, xystd, ef, n);
        int slice = ((ne + ns - 1) / ns + 1) & ~1;   // even slice; ne even
        if (sw) {
            scan_kernel<true><<<nb * ns, 1024, 0, stream>>>(
                eidx, eidx + ne, (const float2*)eattr, ef, edgemean, edgestd,
                partial, ne, nb, slice);
        } else {
            scan_kernel<false><<<nb * ns, 1024, 0, stream>>>(
                eidx, eidx + ne, (const float2*)eattr, ef, edgemean, edgestd,
                partial, ne, nb, slice);
        }
        reduce_kernel<<<(n + 255) / 256, 256, 0, stream>>>(
            x, y, xymean, xystd, partial, out, n, nb, ns);
    } else {
        float2* agg = (float2*)d_ws;
        float2* ef = (float2*)((char*)d_ws + (size_t)n * sizeof(float2));
        (void)hipMemsetAsync(agg, 0, (size_t)n * sizeof(float2), stream);
        node_ef_kernel<<<(n + 255) / 256, 256, 0, stream>>>(x, xymean, xystd, ef, n);
        edge_atomic_kernel<<<(ne + 255) / 256, 256, 0, stream>>>(
            eidx, (const float2*)eattr, ef, edgemean, edgestd, (float*)agg, ne);
        reduce_kernel<<<(n + 255) / 256, 256, 0, stream>>>(
            x, y, xymean, xystd, agg, out, n, nb, 0);
    }
}